// Round 10
// baseline (415.767 us; speedup 1.0000x reference)
//
#include <hip/hip_runtime.h>

typedef unsigned short u16;
typedef __attribute__((ext_vector_type(8))) short bf16x8;
typedef __attribute__((ext_vector_type(4))) float f32x4;
typedef __attribute__((ext_vector_type(8))) u16 u16x8;

#define GLOAD_LDS(g, s) __builtin_amdgcn_global_load_lds( \
    (const __attribute__((address_space(1))) void*)(g),   \
    (__attribute__((address_space(3))) void*)(s), 16, 0, 0)

__device__ __forceinline__ u16 f2bf(float f) {
  union { float f; unsigned u; } v; v.f = f;
  unsigned r = v.u + 0x7fffu + ((v.u >> 16) & 1u);
  return (u16)(r >> 16);
}
__device__ __forceinline__ float bf2f(u16 h) {
  union { unsigned u; float f; } v; v.u = ((unsigned)h) << 16;
  return v.f;
}

// inline-asm ds_read_b128 (counted lgkmcnt by hand, rule #18)
__device__ __forceinline__ unsigned lds_a(const u16* p) {
  return (unsigned)(unsigned long long)(__attribute__((address_space(3))) const u16*)p;
}
__device__ __forceinline__ bf16x8 ds128(const u16* p) {
  bf16x8 r;
  asm volatile("ds_read_b128 %0, %1" : "=v"(r) : "v"(lds_a(p)));
  return r;
}

// ================= OLD 128x128 BK=32 core (k_proj only) =================
__device__ __forceinline__ void stage_pair(const u16* gA, int lda, const u16* gB, int ldb,
                                           u16* lA, u16* lB, int wave, int lane) {
  int row = (wave << 4) + (lane >> 2);
  int kb  = (lane & 3) << 3;
  GLOAD_LDS(gA + row * lda + kb,        lA + (wave << 9));
  GLOAD_LDS(gA + (row + 64) * lda + kb, lA + ((wave + 4) << 9));
  GLOAD_LDS(gB + row * ldb + kb,        lB + (wave << 9));
  GLOAD_LDS(gB + (row + 64) * ldb + kb, lB + ((wave + 4) << 9));
}

__device__ __forceinline__ void gemm_seg(f32x4 (&acc)[4][4],
    const u16* Ag, const u16* Bg, int lda, int ldb, int nk,
    u16* As, u16* Bs, int wave, int lane) {
  const int wr = (wave >> 1) << 6, wc = (wave & 1) << 6;
  const int rl = lane & 15, rk = (lane >> 4) << 3;
  stage_pair(Ag, lda, Bg, ldb, As, Bs, wave, lane);
  if (nk > 1)
    stage_pair(Ag + 32, lda, Bg + 32, ldb, As + 4096, Bs + 4096, wave, lane);
  int bufsel = 0;
  for (int kt = 0; kt < nk; ++kt) {
    if (kt + 1 < nk) asm volatile("s_waitcnt vmcnt(4)" ::: "memory");
    else             asm volatile("s_waitcnt vmcnt(0)" ::: "memory");
    __builtin_amdgcn_s_barrier();
    asm volatile("" ::: "memory");
    if (kt + 2 < nk) {
      int nb = bufsel + 2; if (nb >= 3) nb -= 3;
      stage_pair(Ag + (long)(kt + 2) * 32, lda, Bg + (long)(kt + 2) * 32, ldb,
                 As + nb * 4096, Bs + nb * 4096, wave, lane);
    }
    const u16* ab = As + bufsel * 4096;
    const u16* bb = Bs + bufsel * 4096;
    bf16x8 af[4], bfr[4];
#pragma unroll
    for (int i = 0; i < 4; i++)
      af[i]  = *(const bf16x8*)(ab + ((wr + (i << 4) + rl) << 5) + rk);
#pragma unroll
    for (int j = 0; j < 4; j++)
      bfr[j] = *(const bf16x8*)(bb + ((wc + (j << 4) + rl) << 5) + rk);
#pragma unroll
    for (int i = 0; i < 4; i++)
#pragma unroll
      for (int j = 0; j < 4; j++)
        acc[i][j] = __builtin_amdgcn_mfma_f32_16x16x32_bf16(af[i], bfr[j], acc[i][j], 0, 0, 0);
    __builtin_amdgcn_sched_barrier(0);
    bufsel = bufsel + 1; if (bufsel == 3) bufsel = 0;
  }
}

// ====== 256x256 8-wave BK=64 core, A-deep(3buf)/B-shallow(2buf), 160KB LDS ======
// As[3][256][64] = 96KB (streaming operand, prefetch depth 2 covers L3 latency)
// Bs[2][256][64] = 64KB (L2-hot operand via XCD grouping, depth 1)
// Per tile: wait vmcnt(4) [A(t),B(t) landed, A(t+1) stays in flight] -> barrier
// -> issue B(t+1), A(t+2) -> compute. vmcnt(0) only at final tile.
// Swizzle g^(row&7) on both stage source and ds_read (0-conflict, r5-r9).

__device__ __forceinline__ void stage_one(const u16* g, int ld, u16* d, int tid) {
  int rw = tid >> 3;                          // 0..63 (row within 64-row pass)
  int gs = ((tid & 7) ^ (rw & 7)) << 3;       // swizzled k-offset (elems)
  int wb = (tid >> 6) << 9;                   // wave-uniform LDS base (elems)
#pragma unroll
  for (int p = 0; p < 4; p++)
    GLOAD_LDS(g + (long)(p * 64 + rw) * ld + gs, d + p * 4096 + wb);
}

__device__ __forceinline__ void gemm256d(f32x4 (&acc)[8][4],
    const u16* Ag, int lda, const u16* Bg, int ldb, int nk,
    u16* As, u16* Bs, int tid) {
  const int lane = tid & 63, wid = tid >> 6;
  const int wr = (wid >> 2) << 7;             // 0 / 128
  const int wc = (wid & 3) << 6;              // 0 / 64 / 128 / 192
  const int rl = lane & 15, kg = lane >> 4;
  const int swz0 = (kg ^ (rl & 7)) << 3;
  const int rbA = (wr + rl) * 64, rbB = (wc + rl) * 64;

  // prologue: A(0), B(0), A(1)  (12 loads/thread order = steady-state pattern)
  stage_one(Ag, lda, As, tid);
  stage_one(Bg, ldb, Bs, tid);
  if (nk > 1) stage_one(Ag + 64, lda, As + 16384, tid);

  int ba = 0;
  for (int t = 0; t < nk; ++t) {
    if (t + 1 < nk) asm volatile("s_waitcnt vmcnt(4)" ::: "memory");  // A(t),B(t) landed
    else            asm volatile("s_waitcnt vmcnt(0)" ::: "memory");
    __builtin_amdgcn_s_barrier();              // all waves staged + prev reads done
    if (t + 1 < nk)
      stage_one(Bg + (t + 1) * 64, ldb, Bs + ((t + 1) & 1) * 16384, tid);
    if (t + 2 < nk) {
      int nb = ba + 2; if (nb >= 3) nb -= 3;
      stage_one(Ag + (long)(t + 2) * 64, lda, As + nb * 16384, tid);
    }
    const u16* ab = As + ba * 16384 + rbA;
    const u16* bb = Bs + (t & 1) * 16384 + rbB;
#pragma unroll
    for (int kk = 0; kk < 2; kk++) {
      const int sw = swz0 ^ (kk << 5);
      bf16x8 a[8], b[4];
#pragma unroll
      for (int i = 0; i < 8; i++) a[i] = ds128(ab + i * 1024 + sw);
#pragma unroll
      for (int j = 0; j < 4; j++) b[j] = ds128(bb + j * 1024 + sw);
      asm volatile("s_waitcnt lgkmcnt(0)" ::: "memory");
      __builtin_amdgcn_sched_barrier(0);
      __builtin_amdgcn_s_setprio(1);
#pragma unroll
      for (int i = 0; i < 8; i++)
#pragma unroll
        for (int j = 0; j < 4; j++)
          acc[i][j] = __builtin_amdgcn_mfma_f32_16x16x32_bf16(a[i], b[j], acc[i][j], 0, 0, 0);
      __builtin_amdgcn_s_setprio(0);
      __builtin_amdgcn_sched_barrier(0);
    }
    ba = ba + 1; if (ba == 3) ba = 0;
  }
}

// ---------------- conversion kernels ----------------
__global__ __launch_bounds__(256) void k_cvt2(const float* __restrict__ inX,
                                              const float* __restrict__ inY,
                                              u16* __restrict__ oX, u16* __restrict__ oY,
                                              int n8) {
  int i = blockIdx.x * 256 + threadIdx.x;
  const float* in = (i < n8) ? inX : inY;
  u16* out = (i < n8) ? oX : oY;
  int k = (i < n8) ? i : i - n8;
  const float4* pf = (const float4*)in + (long)k * 2;
  float4 a = pf[0], b = pf[1];
  u16x8 o;
  o[0] = f2bf(a.x); o[1] = f2bf(a.y); o[2] = f2bf(a.z); o[3] = f2bf(a.w);
  o[4] = f2bf(b.x); o[5] = f2bf(b.y); o[6] = f2bf(b.z); o[7] = f2bf(b.w);
  *((u16x8*)out + k) = o;
}

struct P6 { const float* p[6]; };
struct O6 { u16* p[6]; };

__global__ __launch_bounds__(256) void k_cvt_w(P6 w, u16* __restrict__ out) {
  int z = blockIdx.y;
  int i = blockIdx.x * 256 + threadIdx.x;
  const float4* pf = (const float4*)w.p[z] + (long)i * 2;
  float4 a = pf[0], b = pf[1];
  u16x8 o;
  o[0] = f2bf(a.x); o[1] = f2bf(a.y); o[2] = f2bf(a.z); o[3] = f2bf(a.w);
  o[4] = f2bf(b.x); o[5] = f2bf(b.y); o[6] = f2bf(b.z); o[7] = f2bf(b.w);
  *((u16x8*)(out + (long)z * 262144) + i) = o;
}

// ---------------- projections (old core, 1D bm-chunked grid) ----------------
__global__ __launch_bounds__(256) void k_proj(const u16* __restrict__ Xb, const u16* __restrict__ Yb,
                                              const u16* __restrict__ Wb, P6 bias, O6 dst) {
  __shared__ u16 As[12288], Bs[12288];
  int x = blockIdx.x;
  int swz = (x & 7) * 384 + (x >> 3);
  int bm = swz / 24;
  int r  = swz - bm * 24;
  int z = r >> 2, bn = r & 3;
  int tid = threadIdx.x, wave = tid >> 6, lane = tid & 63;
  const u16* Ag = (z < 3 ? Xb : Yb) + (long)bm * 128 * 512;
  const u16* Bg = Wb + (long)z * 262144 + (long)bn * 128 * 512;
  f32x4 acc[4][4] = {};
  gemm_seg(acc, Ag, Bg, 512, 512, 16, As, Bs, wave, lane);
  const float* bi = bias.p[z];
  u16* D = dst.p[z];
  int wr = (wave >> 1) << 6, wc = (wave & 1) << 6;
  int row0 = bm * 128 + wr + ((lane >> 4) << 2);
  int col0 = bn * 128 + wc + (lane & 15);
  float bj[4];
#pragma unroll
  for (int j = 0; j < 4; j++) bj[j] = bi[col0 + (j << 4)];
#pragma unroll
  for (int i = 0; i < 4; i++)
#pragma unroll
    for (int j = 0; j < 4; j++)
#pragma unroll
      for (int rr = 0; rr < 4; rr++)
        D[(long)(row0 + (i << 4) + rr) * 512 + col0 + (j << 4)] = f2bf(acc[i][j][rr] + bj[j]);
}

// ---------------- scores (256² A-deep core): XCD chunk = one batch b ----------------
__global__ __launch_bounds__(512) void k_s(const u16* __restrict__ Q, const u16* __restrict__ K,
                                           u16* __restrict__ S) {
  __shared__ u16 As[49152], Bs[32768];
  int x = blockIdx.x;
  int swz = (x & 7) * 64 + (x >> 3);         // 512 blocks, chunk=64 = one b
  int bn = swz & 7, bm = (swz >> 3) & 7, b = swz >> 6;
  int tid = threadIdx.x;
  const u16* Ag = Q + (long)b * 1048576 + (long)bm * 256 * 512;
  const u16* Bg = K + (long)b * 1048576 + (long)bn * 256 * 512;
  f32x4 acc[8][4] = {};
  gemm256d(acc, Ag, 512, Bg, 512, 8, As, Bs, tid);
  u16* D = S + (long)b * 4194304;
  const float scale = 0.04419417382415922f;  // 1/sqrt(512)
  int lane = tid & 63, wid = tid >> 6;
  int row0 = bm * 256 + ((wid >> 2) << 7) + ((lane >> 4) << 2);
  int col0 = bn * 256 + ((wid & 3) << 6) + (lane & 15);
#pragma unroll
  for (int i = 0; i < 8; i++)
#pragma unroll
    for (int j = 0; j < 4; j++)
#pragma unroll
      for (int rr = 0; rr < 4; rr++)
        D[(long)(row0 + (i << 4) + rr) * 2048 + col0 + (j << 4)] = f2bf(acc[i][j][rr] * scale);
}

// ---------------- softmax over batch axis ----------------
__global__ __launch_bounds__(256) void k_softmax(u16* __restrict__ S) {
  int idx = blockIdx.x * 256 + threadIdx.x;
  u16x8 v[8];
#pragma unroll
  for (int b = 0; b < 8; b++) v[b] = *((const u16x8*)(S + (long)b * 4194304) + idx);
#pragma unroll
  for (int j = 0; j < 8; j++) {
    float e[8], m = -1e30f;
#pragma unroll
    for (int b = 0; b < 8; b++) { e[b] = bf2f(v[b][j]); m = fmaxf(m, e[b]); }
    float s = 0.f;
#pragma unroll
    for (int b = 0; b < 8; b++) { e[b] = __expf(e[b] - m); s += e[b]; }
    float inv = 1.0f / s;
#pragma unroll
    for (int b = 0; b < 8; b++) v[b][j] = f2bf(e[b] * inv);
  }
#pragma unroll
  for (int b = 0; b < 8; b++) *((u16x8*)(S + (long)b * 4194304) + idx) = v[b];
}

// ---------------- V transpose ----------------
__global__ __launch_bounds__(256) void k_tr(const u16* __restrict__ V1, const u16* __restrict__ V2,
                                            u16* __restrict__ T1, u16* __restrict__ T2) {
  __shared__ u16 tile[64][65];
  int z = blockIdx.z;
  const u16* src = (z < 8 ? V1 : V2) + (long)(z & 7) * 1048576;
  u16*       dst = (z < 8 ? T1 : T2) + (long)(z & 7) * 1048576;
  int n0 = blockIdx.x * 64, d0 = blockIdx.y * 64;
  int t = threadIdx.x;
  int r = t >> 2, cs = (t & 3) * 16;
  const u16x8* sp = (const u16x8*)(src + (long)(n0 + r) * 512 + d0 + cs);
  u16x8 a = sp[0], b = sp[1];
#pragma unroll
  for (int jj = 0; jj < 8; jj++) { tile[r][cs + jj] = a[jj]; tile[r][cs + 8 + jj] = b[jj]; }
  __syncthreads();
  u16x8 o0, o1;
#pragma unroll
  for (int jj = 0; jj < 8; jj++) { o0[jj] = tile[cs + jj][r]; o1[jj] = tile[cs + 8 + jj][r]; }
  u16x8* op = (u16x8*)(dst + (long)(d0 + r) * 2048 + n0 + cs);
  op[0] = o0; op[1] = o1;
}

// ---------------- PV (256² A-deep core, K-split 2): kc0 -> out, kc1 -> Pbuf ----------------
// mode 0 (first PV):  kc0: out = acc + X + Y ; kc1: P = acc
// mode 1 (second PV): kc0: out += acc        ; kc1: P += acc
__global__ __launch_bounds__(512) void k_pv(const u16* __restrict__ A, const u16* __restrict__ Vt,
                                            const float* __restrict__ X, const float* __restrict__ Y,
                                            float* __restrict__ out, float* __restrict__ P,
                                            int mode) {
  __shared__ u16 As[49152], Bs[32768];
  int x = blockIdx.x;
  int swz = (x & 7) * 32 + (x >> 3);         // 256 blocks, chunk=32 = one b
  int kc = swz & 1, bn = (swz >> 1) & 1, bm = (swz >> 2) & 7, b = swz >> 5;
  int tid = threadIdx.x;
  const u16* Ag = A + (long)b * 4194304 + (long)bm * 256 * 2048 + kc * 1024;
  const u16* Bg = Vt + (long)b * 1048576 + (long)bn * 256 * 2048 + kc * 1024;
  f32x4 acc[8][4] = {};
  gemm256d(acc, Ag, 2048, Bg, 2048, 16, As, Bs, tid);
  int lane = tid & 63, wid = tid >> 6;
  int row0 = bm * 256 + ((wid >> 2) << 7) + ((lane >> 4) << 2);
  int col0 = bn * 256 + ((wid & 3) << 6) + (lane & 15);
  long base = (long)b * 1048576;
  float* D = kc ? P : out;
#pragma unroll
  for (int i = 0; i < 8; i++)
#pragma unroll
    for (int j = 0; j < 4; j++)
#pragma unroll
      for (int rr = 0; rr < 4; rr++) {
        long idx = base + (long)(row0 + (i << 4) + rr) * 512 + col0 + (j << 4);
        float v = acc[i][j][rr];
        if (mode) D[idx] += v;
        else      D[idx] = kc ? v : (v + X[idx] + Y[idx]);
      }
}

// ---------------- final: out += P ----------------
__global__ __launch_bounds__(256) void k_fin(float* __restrict__ out, const float* __restrict__ P) {
  long i = (long)(blockIdx.x * 256 + threadIdx.x) * 4;
  float4 o = *(const float4*)(out + i);
  float4 p = *(const float4*)(P + i);
  o.x += p.x; o.y += p.y; o.z += p.z; o.w += p.w;
  *(float4*)(out + i) = o;
}

extern "C" void kernel_launch(void* const* d_in, const int* in_sizes, int n_in,
                              void* d_out, int out_size, void* d_ws, size_t ws_size,
                              hipStream_t stream) {
  const float* X = (const float*)d_in[0];
  const float* Y = (const float*)d_in[1];
  P6 wp, bp;
  for (int i = 0; i < 6; i++) { wp.p[i] = (const float*)d_in[2 + 2 * i]; bp.p[i] = (const float*)d_in[3 + 2 * i]; }

  const long NX = 8L * 2048 * 512;
  const long NS = 8L * 2048 * 2048;
  u16* p = (u16*)d_ws;
  u16* Xb = p;  p += NX;                  // bf16 X (reused as Vt1)
  u16* Yb = p;  p += NX;                  // bf16 Y (reused as Vt2)
  u16* Wb = p;  p += 6L * 512 * 512;
  u16* Q1 = p;  p += NX;
  u16* K2 = p;  p += NX;
  u16* Q2 = p;  p += NX;                  // Q2+K1 become f32 Pbuf after S2
  u16* K1 = p;  p += NX;
  u16* Sb = p;  p += NS;
  u16* V1 = Sb;
  u16* V2 = Sb + NX;
  u16* Vt1 = Xb;
  u16* Vt2 = Yb;
  float* Pbuf = (float*)Q2;               // NX floats (33.5 MB)
  (void)ws_size; (void)in_sizes; (void)n_in; (void)out_size;

  dim3 T(256);
  k_cvt2<<<dim3(8192), T, 0, stream>>>(X, Y, Xb, Yb, (int)(NX / 8));
  k_cvt_w<<<dim3(128, 6), T, 0, stream>>>(wp, Wb);
  O6 dst; dst.p[0] = Q1; dst.p[1] = K1; dst.p[2] = V1; dst.p[3] = Q2; dst.p[4] = K2; dst.p[5] = V2;
  k_proj<<<dim3(3072), T, 0, stream>>>(Xb, Yb, Wb, bp, dst);
  k_tr<<<dim3(32, 8, 16), T, 0, stream>>>(V1, V2, Vt1, Vt2);
  // attention 2 first: S2 = Q2.K1^T, softmax over b, PV2 (frees Q2/K1 -> Pbuf)
  k_s<<<dim3(512), dim3(512), 0, stream>>>(Q2, K1, Sb);
  k_softmax<<<dim3(2048), T, 0, stream>>>(Sb);
  k_pv<<<dim3(256), dim3(512), 0, stream>>>(Sb, Vt1, X, Y, (float*)d_out, Pbuf, 0);
  // attention 1: S1 = Q1.K2^T, softmax, PV1 accumulates
  k_s<<<dim3(512), dim3(512), 0, stream>>>(Q1, K2, Sb);
  k_softmax<<<dim3(2048), T, 0, stream>>>(Sb);
  k_pv<<<dim3(256), dim3(512), 0, stream>>>(Sb, Vt2, X, Y, (float*)d_out, Pbuf, 1);
  // out += P
  k_fin<<<dim3((int)(NX / 1024)), T, 0, stream>>>((float*)d_out, Pbuf);
}

// Round 11
// 405.709 us; speedup vs baseline: 1.0248x; 1.0248x over previous
//
#include <hip/hip_runtime.h>

typedef unsigned short u16;
typedef __attribute__((ext_vector_type(8))) short bf16x8;
typedef __attribute__((ext_vector_type(4))) float f32x4;
typedef __attribute__((ext_vector_type(8))) u16 u16x8;

#define GLOAD_LDS(g, s) __builtin_amdgcn_global_load_lds( \
    (const __attribute__((address_space(1))) void*)(g),   \
    (__attribute__((address_space(3))) void*)(s), 16, 0, 0)

__device__ __forceinline__ u16 f2bf(float f) {
  union { float f; unsigned u; } v; v.f = f;
  unsigned r = v.u + 0x7fffu + ((v.u >> 16) & 1u);
  return (u16)(r >> 16);
}
__device__ __forceinline__ float bf2f(u16 h) {
  union { unsigned u; float f; } v; v.u = ((unsigned)h) << 16;
  return v.f;
}

// inline-asm ds_read_b128 (counted lgkmcnt by hand, rule #18)
__device__ __forceinline__ unsigned lds_a(const u16* p) {
  return (unsigned)(unsigned long long)(__attribute__((address_space(3))) const u16*)p;
}
__device__ __forceinline__ bf16x8 ds128(const u16* p) {
  bf16x8 r;
  asm volatile("ds_read_b128 %0, %1" : "=v"(r) : "v"(lds_a(p)));
  return r;
}

// ================= OLD 128x128 BK=32 core (k_proj only) =================
__device__ __forceinline__ void stage_pair(const u16* gA, int lda, const u16* gB, int ldb,
                                           u16* lA, u16* lB, int wave, int lane) {
  int row = (wave << 4) + (lane >> 2);
  int kb  = (lane & 3) << 3;
  GLOAD_LDS(gA + row * lda + kb,        lA + (wave << 9));
  GLOAD_LDS(gA + (row + 64) * lda + kb, lA + ((wave + 4) << 9));
  GLOAD_LDS(gB + row * ldb + kb,        lB + (wave << 9));
  GLOAD_LDS(gB + (row + 64) * ldb + kb, lB + ((wave + 4) << 9));
}

__device__ __forceinline__ void gemm_seg(f32x4 (&acc)[4][4],
    const u16* Ag, const u16* Bg, int lda, int ldb, int nk,
    u16* As, u16* Bs, int wave, int lane) {
  const int wr = (wave >> 1) << 6, wc = (wave & 1) << 6;
  const int rl = lane & 15, rk = (lane >> 4) << 3;
  stage_pair(Ag, lda, Bg, ldb, As, Bs, wave, lane);
  if (nk > 1)
    stage_pair(Ag + 32, lda, Bg + 32, ldb, As + 4096, Bs + 4096, wave, lane);
  int bufsel = 0;
  for (int kt = 0; kt < nk; ++kt) {
    if (kt + 1 < nk) asm volatile("s_waitcnt vmcnt(4)" ::: "memory");
    else             asm volatile("s_waitcnt vmcnt(0)" ::: "memory");
    __builtin_amdgcn_s_barrier();
    asm volatile("" ::: "memory");
    if (kt + 2 < nk) {
      int nb = bufsel + 2; if (nb >= 3) nb -= 3;
      stage_pair(Ag + (long)(kt + 2) * 32, lda, Bg + (long)(kt + 2) * 32, ldb,
                 As + nb * 4096, Bs + nb * 4096, wave, lane);
    }
    const u16* ab = As + bufsel * 4096;
    const u16* bb = Bs + bufsel * 4096;
    bf16x8 af[4], bfr[4];
#pragma unroll
    for (int i = 0; i < 4; i++)
      af[i]  = *(const bf16x8*)(ab + ((wr + (i << 4) + rl) << 5) + rk);
#pragma unroll
    for (int j = 0; j < 4; j++)
      bfr[j] = *(const bf16x8*)(bb + ((wc + (j << 4) + rl) << 5) + rk);
#pragma unroll
    for (int i = 0; i < 4; i++)
#pragma unroll
      for (int j = 0; j < 4; j++)
        acc[i][j] = __builtin_amdgcn_mfma_f32_16x16x32_bf16(af[i], bfr[j], acc[i][j], 0, 0, 0);
    __builtin_amdgcn_sched_barrier(0);
    bufsel = bufsel + 1; if (bufsel == 3) bufsel = 0;
  }
}

// ====== 256x256 8-wave BK=64 PHASED core, 2-buffer, 128KB LDS ======
// Each operand buffer = 2 k-half planes [256 rows][32 elems] (16KB each).
// Per K-tile, 4 phases; each phase issues ONE plane-stage (2 loads/thread)
// for tile t+1 and computes a quarter of tile t's MFMAs -> steady issue.
// Waits: {vmcnt(4) + barrier} at P0 and P2 only (in-order retirement:
// oldest 4 = exactly the 2 planes consumed in the next 2 phases). Never
// drains mid-loop. Swizzle: granule g stored at g^(row&3) (both sides).

__device__ __forceinline__ void stage_plane(const u16* g, int ld, u16* d, int tid) {
  int w = tid >> 6, l = tid & 63;
#pragma unroll
  for (int q = 0; q < 2; q++) {
    int ch = (w << 1) + q;                   // 16-row chunk 0..15
    int row = (ch << 4) + (l >> 2);
    int gs = (((l & 3) ^ (row & 3)) << 3);   // swizzled granule (elems)
    GLOAD_LDS(g + (long)row * ld + gs, d + (ch << 9));
  }
}

#define MFMA16(ACC, IOFF)                                                        \
  asm volatile("s_waitcnt lgkmcnt(0)" ::: "memory");                             \
  __builtin_amdgcn_sched_barrier(0);                                             \
  __builtin_amdgcn_s_setprio(1);                                                 \
  _Pragma("unroll")                                                              \
  for (int i = 0; i < 4; i++)                                                    \
    _Pragma("unroll")                                                            \
    for (int j = 0; j < 4; j++)                                                  \
      ACC[i + IOFF][j] = __builtin_amdgcn_mfma_f32_16x16x32_bf16(a[i], b[j],     \
                                                ACC[i + IOFF][j], 0, 0, 0);      \
  __builtin_amdgcn_s_setprio(0);                                                 \
  __builtin_amdgcn_sched_barrier(0);

__device__ __forceinline__ void gemm256p(f32x4 (&acc)[8][4],
    const u16* Ag, int lda, const u16* Bg, int ldb, int nk,
    u16* As, u16* Bs, int tid) {
  const int lane = tid & 63, wid = tid >> 6;
  const int wr = (wid >> 2) << 7, wc = (wid & 3) << 6;   // 2M x 4N waves
  const int rl = lane & 15, kg = lane >> 4;
  const int swzr = (kg ^ (rl & 3)) << 3;
  const int oA = (wr + rl) * 32 + swzr;
  const int oB = (wc + rl) * 32 + swzr;

  // prologue: 4 planes of tile 0 in consumption order
  stage_plane(Ag,      lda, As,        tid);   // A-k0
  stage_plane(Bg,      ldb, Bs,        tid);   // B-k0
  stage_plane(Ag + 32, lda, As + 8192, tid);   // A-k1
  stage_plane(Bg + 32, ldb, Bs + 8192, tid);   // B-k1

  for (int t = 0; t < nk; ++t) {
    const int cur = (t & 1) << 14, nxt = cur ^ 16384;
    const u16* gA1 = Ag + (long)(t + 1) * 64;
    const u16* gB1 = Bg + (long)(t + 1) * 64;
    const bool more = (t + 1 < nk);
    bf16x8 a[4], b[4];
    // ---- P0: wait k0 planes; stage A-k0(t+1); MFMA kk0 i0-3 ----
    asm volatile("s_waitcnt vmcnt(4)" ::: "memory");
    __builtin_amdgcn_s_barrier();
    if (more) stage_plane(gA1, lda, As + nxt, tid);
    {
      const u16* pa = As + cur + oA;
      const u16* pb = Bs + cur + oB;
#pragma unroll
      for (int i = 0; i < 4; i++) a[i] = ds128(pa + i * 512);
#pragma unroll
      for (int j = 0; j < 4; j++) b[j] = ds128(pb + j * 512);
      MFMA16(acc, 0)
      // ---- P1: stage B-k0(t+1); MFMA kk0 i4-7 (reuse b) ----
      if (more) stage_plane(gB1, ldb, Bs + nxt, tid);
#pragma unroll
      for (int i = 0; i < 4; i++) a[i] = ds128(pa + (i + 4) * 512);
      MFMA16(acc, 4)
    }
    // ---- P2: wait k1 planes; stage A-k1(t+1); MFMA kk1 i0-3 ----
    if (more) asm volatile("s_waitcnt vmcnt(4)" ::: "memory");
    else      asm volatile("s_waitcnt vmcnt(0)" ::: "memory");
    __builtin_amdgcn_s_barrier();
    if (more) stage_plane(gA1 + 32, lda, As + nxt + 8192, tid);
    {
      const u16* pa = As + cur + 8192 + oA;
      const u16* pb = Bs + cur + 8192 + oB;
#pragma unroll
      for (int i = 0; i < 4; i++) a[i] = ds128(pa + i * 512);
#pragma unroll
      for (int j = 0; j < 4; j++) b[j] = ds128(pb + j * 512);
      MFMA16(acc, 0)
      // ---- P3: stage B-k1(t+1); MFMA kk1 i4-7 (reuse b) ----
      if (more) stage_plane(gB1 + 32, ldb, Bs + nxt + 8192, tid);
#pragma unroll
      for (int i = 0; i < 4; i++) a[i] = ds128(pa + (i + 4) * 512);
      MFMA16(acc, 4)
    }
  }
}

// ---------------- conversion kernels ----------------
__global__ __launch_bounds__(256) void k_cvt2(const float* __restrict__ inX,
                                              const float* __restrict__ inY,
                                              u16* __restrict__ oX, u16* __restrict__ oY,
                                              int n8) {
  int i = blockIdx.x * 256 + threadIdx.x;
  const float* in = (i < n8) ? inX : inY;
  u16* out = (i < n8) ? oX : oY;
  int k = (i < n8) ? i : i - n8;
  const float4* pf = (const float4*)in + (long)k * 2;
  float4 a = pf[0], b = pf[1];
  u16x8 o;
  o[0] = f2bf(a.x); o[1] = f2bf(a.y); o[2] = f2bf(a.z); o[3] = f2bf(a.w);
  o[4] = f2bf(b.x); o[5] = f2bf(b.y); o[6] = f2bf(b.z); o[7] = f2bf(b.w);
  *((u16x8*)out + k) = o;
}

struct P6 { const float* p[6]; };
struct O6 { u16* p[6]; };

__global__ __launch_bounds__(256) void k_cvt_w(P6 w, u16* __restrict__ out) {
  int z = blockIdx.y;
  int i = blockIdx.x * 256 + threadIdx.x;
  const float4* pf = (const float4*)w.p[z] + (long)i * 2;
  float4 a = pf[0], b = pf[1];
  u16x8 o;
  o[0] = f2bf(a.x); o[1] = f2bf(a.y); o[2] = f2bf(a.z); o[3] = f2bf(a.w);
  o[4] = f2bf(b.x); o[5] = f2bf(b.y); o[6] = f2bf(b.z); o[7] = f2bf(b.w);
  *((u16x8*)(out + (long)z * 262144) + i) = o;
}

// ---------------- projections (old core, 1D bm-chunked grid) ----------------
__global__ __launch_bounds__(256) void k_proj(const u16* __restrict__ Xb, const u16* __restrict__ Yb,
                                              const u16* __restrict__ Wb, P6 bias, O6 dst) {
  __shared__ u16 As[12288], Bs[12288];
  int x = blockIdx.x;
  int swz = (x & 7) * 384 + (x >> 3);
  int bm = swz / 24;
  int r  = swz - bm * 24;
  int z = r >> 2, bn = r & 3;
  int tid = threadIdx.x, wave = tid >> 6, lane = tid & 63;
  const u16* Ag = (z < 3 ? Xb : Yb) + (long)bm * 128 * 512;
  const u16* Bg = Wb + (long)z * 262144 + (long)bn * 128 * 512;
  f32x4 acc[4][4] = {};
  gemm_seg(acc, Ag, Bg, 512, 512, 16, As, Bs, wave, lane);
  const float* bi = bias.p[z];
  u16* D = dst.p[z];
  int wr = (wave >> 1) << 6, wc = (wave & 1) << 6;
  int row0 = bm * 128 + wr + ((lane >> 4) << 2);
  int col0 = bn * 128 + wc + (lane & 15);
  float bj[4];
#pragma unroll
  for (int j = 0; j < 4; j++) bj[j] = bi[col0 + (j << 4)];
#pragma unroll
  for (int i = 0; i < 4; i++)
#pragma unroll
    for (int j = 0; j < 4; j++)
#pragma unroll
      for (int rr = 0; rr < 4; rr++)
        D[(long)(row0 + (i << 4) + rr) * 512 + col0 + (j << 4)] = f2bf(acc[i][j][rr] + bj[j]);
}

// ---------------- scores (phased 256² core): XCD chunk = one batch b ----------------
__global__ __launch_bounds__(512) void k_s(const u16* __restrict__ Q, const u16* __restrict__ K,
                                           u16* __restrict__ S) {
  __shared__ u16 As[32768], Bs[32768];
  int x = blockIdx.x;
  int swz = (x & 7) * 64 + (x >> 3);         // 512 blocks, chunk=64 = one b
  int bn = swz & 7, bm = (swz >> 3) & 7, b = swz >> 6;
  int tid = threadIdx.x;
  const u16* Ag = Q + (long)b * 1048576 + (long)bm * 256 * 512;
  const u16* Bg = K + (long)b * 1048576 + (long)bn * 256 * 512;
  f32x4 acc[8][4] = {};
  gemm256p(acc, Ag, 512, Bg, 512, 8, As, Bs, tid);
  u16* D = S + (long)b * 4194304;
  const float scale = 0.04419417382415922f;  // 1/sqrt(512)
  int lane = tid & 63, wid = tid >> 6;
  int row0 = bm * 256 + ((wid >> 2) << 7) + ((lane >> 4) << 2);
  int col0 = bn * 256 + ((wid & 3) << 6) + (lane & 15);
#pragma unroll
  for (int i = 0; i < 8; i++)
#pragma unroll
    for (int j = 0; j < 4; j++)
#pragma unroll
      for (int rr = 0; rr < 4; rr++)
        D[(long)(row0 + (i << 4) + rr) * 2048 + col0 + (j << 4)] = f2bf(acc[i][j][rr] * scale);
}

// ---------------- softmax over batch axis ----------------
__global__ __launch_bounds__(256) void k_softmax(u16* __restrict__ S) {
  int idx = blockIdx.x * 256 + threadIdx.x;
  u16x8 v[8];
#pragma unroll
  for (int b = 0; b < 8; b++) v[b] = *((const u16x8*)(S + (long)b * 4194304) + idx);
#pragma unroll
  for (int j = 0; j < 8; j++) {
    float e[8], m = -1e30f;
#pragma unroll
    for (int b = 0; b < 8; b++) { e[b] = bf2f(v[b][j]); m = fmaxf(m, e[b]); }
    float s = 0.f;
#pragma unroll
    for (int b = 0; b < 8; b++) { e[b] = __expf(e[b] - m); s += e[b]; }
    float inv = 1.0f / s;
#pragma unroll
    for (int b = 0; b < 8; b++) v[b][j] = f2bf(e[b] * inv);
  }
#pragma unroll
  for (int b = 0; b < 8; b++) *((u16x8*)(S + (long)b * 4194304) + idx) = v[b];
}

// ---------------- V transpose ----------------
__global__ __launch_bounds__(256) void k_tr(const u16* __restrict__ V1, const u16* __restrict__ V2,
                                            u16* __restrict__ T1, u16* __restrict__ T2) {
  __shared__ u16 tile[64][65];
  int z = blockIdx.z;
  const u16* src = (z < 8 ? V1 : V2) + (long)(z & 7) * 1048576;
  u16*       dst = (z < 8 ? T1 : T2) + (long)(z & 7) * 1048576;
  int n0 = blockIdx.x * 64, d0 = blockIdx.y * 64;
  int t = threadIdx.x;
  int r = t >> 2, cs = (t & 3) * 16;
  const u16x8* sp = (const u16x8*)(src + (long)(n0 + r) * 512 + d0 + cs);
  u16x8 a = sp[0], b = sp[1];
#pragma unroll
  for (int jj = 0; jj < 8; jj++) { tile[r][cs + jj] = a[jj]; tile[r][cs + 8 + jj] = b[jj]; }
  __syncthreads();
  u16x8 o0, o1;
#pragma unroll
  for (int jj = 0; jj < 8; jj++) { o0[jj] = tile[cs + jj][r]; o1[jj] = tile[cs + 8 + jj][r]; }
  u16x8* op = (u16x8*)(dst + (long)(d0 + r) * 2048 + n0 + cs);
  op[0] = o0; op[1] = o1;
}

// ---------------- PV (phased 256² core, K-split 2): kc0 -> out, kc1 -> Pbuf ----------------
// mode 0 (first PV):  kc0: out = acc + X + Y ; kc1: P = acc
// mode 1 (second PV): kc0: out += acc        ; kc1: P += acc
__global__ __launch_bounds__(512) void k_pv(const u16* __restrict__ A, const u16* __restrict__ Vt,
                                            const float* __restrict__ X, const float* __restrict__ Y,
                                            float* __restrict__ out, float* __restrict__ P,
                                            int mode) {
  __shared__ u16 As[32768], Bs[32768];
  int x = blockIdx.x;
  int swz = (x & 7) * 32 + (x >> 3);         // 256 blocks, chunk=32 = one b
  int kc = swz & 1, bn = (swz >> 1) & 1, bm = (swz >> 2) & 7, b = swz >> 5;
  int tid = threadIdx.x;
  const u16* Ag = A + (long)b * 4194304 + (long)bm * 256 * 2048 + kc * 1024;
  const u16* Bg = Vt + (long)b * 1048576 + (long)bn * 256 * 2048 + kc * 1024;
  f32x4 acc[8][4] = {};
  gemm256p(acc, Ag, 2048, Bg, 2048, 16, As, Bs, tid);
  int lane = tid & 63, wid = tid >> 6;
  int row0 = bm * 256 + ((wid >> 2) << 7) + ((lane >> 4) << 2);
  int col0 = bn * 256 + ((wid & 3) << 6) + (lane & 15);
  long base = (long)b * 1048576;
  float* D = kc ? P : out;
#pragma unroll
  for (int i = 0; i < 8; i++)
#pragma unroll
    for (int j = 0; j < 4; j++)
#pragma unroll
      for (int rr = 0; rr < 4; rr++) {
        long idx = base + (long)(row0 + (i << 4) + rr) * 512 + col0 + (j << 4);
        float v = acc[i][j][rr];
        if (mode) D[idx] += v;
        else      D[idx] = kc ? v : (v + X[idx] + Y[idx]);
      }
}

// ---------------- final: out += P ----------------
__global__ __launch_bounds__(256) void k_fin(float* __restrict__ out, const float* __restrict__ P) {
  long i = (long)(blockIdx.x * 256 + threadIdx.x) * 4;
  float4 o = *(const float4*)(out + i);
  float4 p = *(const float4*)(P + i);
  o.x += p.x; o.y += p.y; o.z += p.z; o.w += p.w;
  *(float4*)(out + i) = o;
}

extern "C" void kernel_launch(void* const* d_in, const int* in_sizes, int n_in,
                              void* d_out, int out_size, void* d_ws, size_t ws_size,
                              hipStream_t stream) {
  const float* X = (const float*)d_in[0];
  const float* Y = (const float*)d_in[1];
  P6 wp, bp;
  for (int i = 0; i < 6; i++) { wp.p[i] = (const float*)d_in[2 + 2 * i]; bp.p[i] = (const float*)d_in[3 + 2 * i]; }

  const long NX = 8L * 2048 * 512;
  const long NS = 8L * 2048 * 2048;
  u16* p = (u16*)d_ws;
  u16* Xb = p;  p += NX;                  // bf16 X (reused as Vt1)
  u16* Yb = p;  p += NX;                  // bf16 Y (reused as Vt2)
  u16* Wb = p;  p += 6L * 512 * 512;
  u16* Q1 = p;  p += NX;
  u16* K2 = p;  p += NX;
  u16* Q2 = p;  p += NX;                  // Q2+K1 become f32 Pbuf after S2
  u16* K1 = p;  p += NX;
  u16* Sb = p;  p += NS;
  u16* V1 = Sb;
  u16* V2 = Sb + NX;
  u16* Vt1 = Xb;
  u16* Vt2 = Yb;
  float* Pbuf = (float*)Q2;               // NX floats (33.5 MB)
  (void)ws_size; (void)in_sizes; (void)n_in; (void)out_size;

  dim3 T(256);
  k_cvt2<<<dim3(8192), T, 0, stream>>>(X, Y, Xb, Yb, (int)(NX / 8));
  k_cvt_w<<<dim3(128, 6), T, 0, stream>>>(wp, Wb);
  O6 dst; dst.p[0] = Q1; dst.p[1] = K1; dst.p[2] = V1; dst.p[3] = Q2; dst.p[4] = K2; dst.p[5] = V2;
  k_proj<<<dim3(3072), T, 0, stream>>>(Xb, Yb, Wb, bp, dst);
  k_tr<<<dim3(32, 8, 16), T, 0, stream>>>(V1, V2, Vt1, Vt2);
  // attention 2 first: S2 = Q2.K1^T, softmax over b, PV2 (frees Q2/K1 -> Pbuf)
  k_s<<<dim3(512), dim3(512), 0, stream>>>(Q2, K1, Sb);
  k_softmax<<<dim3(2048), T, 0, stream>>>(Sb);
  k_pv<<<dim3(256), dim3(512), 0, stream>>>(Sb, Vt1, X, Y, (float*)d_out, Pbuf, 0);
  // attention 1: S1 = Q1.K2^T, softmax, PV1 accumulates
  k_s<<<dim3(512), dim3(512), 0, stream>>>(Q1, K2, Sb);
  k_softmax<<<dim3(2048), T, 0, stream>>>(Sb);
  k_pv<<<dim3(256), dim3(512), 0, stream>>>(Sb, Vt2, X, Y, (float*)d_out, Pbuf, 1);
  // out += P
  k_fin<<<dim3((int)(NX / 1024)), T, 0, stream>>>((float*)d_out, Pbuf);
}

// Round 12
// 342.253 us; speedup vs baseline: 1.2148x; 1.1854x over previous
//
#include <hip/hip_runtime.h>

typedef unsigned short u16;
typedef unsigned char u8;
typedef __attribute__((ext_vector_type(8))) short bf16x8;
typedef __attribute__((ext_vector_type(4))) float f32x4;
typedef __attribute__((ext_vector_type(8))) u16 u16x8;
typedef __attribute__((ext_vector_type(2))) int i32x2;
typedef __attribute__((ext_vector_type(2))) float f32x2;

#define GLOAD_LDS(g, s) __builtin_amdgcn_global_load_lds( \
    (const __attribute__((address_space(1))) void*)(g),   \
    (__attribute__((address_space(3))) void*)(s), 16, 0, 0)

__device__ __forceinline__ u16 f2bf(float f) {
  union { float f; unsigned u; } v; v.f = f;
  unsigned r = v.u + 0x7fffu + ((v.u >> 16) & 1u);
  return (u16)(r >> 16);
}
__device__ __forceinline__ float bf2f(u16 h) {
  union { unsigned u; float f; } v; v.u = ((unsigned)h) << 16;
  return v.f;
}

__device__ __forceinline__ unsigned lds_addr(const void* p) {
  return (unsigned)(unsigned long long)(__attribute__((address_space(3))) const void*)p;
}
__device__ __forceinline__ bf16x8 ds128(const void* p) {
  bf16x8 r;
  asm volatile("ds_read_b128 %0, %1" : "=v"(r) : "v"(lds_addr(p)));
  return r;
}
__device__ __forceinline__ i32x2 ds64(const void* p) {
  i32x2 r;
  asm volatile("ds_read_b64 %0, %1" : "=v"(r) : "v"(lds_addr(p)));
  return r;
}
// 8 fp8(e4m3) -> 8 bf16 (elem order preserved)
__device__ __forceinline__ bf16x8 cvt8(i32x2 v) {
  f32x2 f0 = __builtin_amdgcn_cvt_pk_f32_fp8(v[0], false);
  f32x2 f1 = __builtin_amdgcn_cvt_pk_f32_fp8(v[0], true);
  f32x2 f2 = __builtin_amdgcn_cvt_pk_f32_fp8(v[1], false);
  f32x2 f3 = __builtin_amdgcn_cvt_pk_f32_fp8(v[1], true);
  unsigned w0, w1, w2, w3;
  asm("v_cvt_pk_bf16_f32 %0, %1, %2" : "=v"(w0) : "v"(f0[0]), "v"(f0[1]));
  asm("v_cvt_pk_bf16_f32 %0, %1, %2" : "=v"(w1) : "v"(f1[0]), "v"(f1[1]));
  asm("v_cvt_pk_bf16_f32 %0, %1, %2" : "=v"(w2) : "v"(f2[0]), "v"(f2[1]));
  asm("v_cvt_pk_bf16_f32 %0, %1, %2" : "=v"(w3) : "v"(f3[0]), "v"(f3[1]));
  union { unsigned w[4]; bf16x8 v8; } u;
  u.w[0] = w0; u.w[1] = w1; u.w[2] = w2; u.w[3] = w3;
  return u.v8;
}

// ================= OLD 128x128 BK=32 core (k_proj only) =================
__device__ __forceinline__ void stage_pair(const u16* gA, int lda, const u16* gB, int ldb,
                                           u16* lA, u16* lB, int wave, int lane) {
  int row = (wave << 4) + (lane >> 2);
  int kb  = (lane & 3) << 3;
  GLOAD_LDS(gA + row * lda + kb,        lA + (wave << 9));
  GLOAD_LDS(gA + (row + 64) * lda + kb, lA + ((wave + 4) << 9));
  GLOAD_LDS(gB + row * ldb + kb,        lB + (wave << 9));
  GLOAD_LDS(gB + (row + 64) * ldb + kb, lB + ((wave + 4) << 9));
}

__device__ __forceinline__ void gemm_seg(f32x4 (&acc)[4][4],
    const u16* Ag, const u16* Bg, int lda, int ldb, int nk,
    u16* As, u16* Bs, int wave, int lane) {
  const int wr = (wave >> 1) << 6, wc = (wave & 1) << 6;
  const int rl = lane & 15, rk = (lane >> 4) << 3;
  stage_pair(Ag, lda, Bg, ldb, As, Bs, wave, lane);
  if (nk > 1)
    stage_pair(Ag + 32, lda, Bg + 32, ldb, As + 4096, Bs + 4096, wave, lane);
  int bufsel = 0;
  for (int kt = 0; kt < nk; ++kt) {
    if (kt + 1 < nk) asm volatile("s_waitcnt vmcnt(4)" ::: "memory");
    else             asm volatile("s_waitcnt vmcnt(0)" ::: "memory");
    __builtin_amdgcn_s_barrier();
    asm volatile("" ::: "memory");
    if (kt + 2 < nk) {
      int nb = bufsel + 2; if (nb >= 3) nb -= 3;
      stage_pair(Ag + (long)(kt + 2) * 32, lda, Bg + (long)(kt + 2) * 32, ldb,
                 As + nb * 4096, Bs + nb * 4096, wave, lane);
    }
    const u16* ab = As + bufsel * 4096;
    const u16* bb = Bs + bufsel * 4096;
    bf16x8 af[4], bfr[4];
#pragma unroll
    for (int i = 0; i < 4; i++)
      af[i]  = *(const bf16x8*)(ab + ((wr + (i << 4) + rl) << 5) + rk);
#pragma unroll
    for (int j = 0; j < 4; j++)
      bfr[j] = *(const bf16x8*)(bb + ((wc + (j << 4) + rl) << 5) + rk);
#pragma unroll
    for (int i = 0; i < 4; i++)
#pragma unroll
      for (int j = 0; j < 4; j++)
        acc[i][j] = __builtin_amdgcn_mfma_f32_16x16x32_bf16(af[i], bfr[j], acc[i][j], 0, 0, 0);
    __builtin_amdgcn_sched_barrier(0);
    bufsel = bufsel + 1; if (bufsel == 3) bufsel = 0;
  }
}

// ====== 256x256 8-wave BK=64 core, A-deep(3buf)/B-shallow(2buf) — k_s ======
// (r10's gemm256d, 0 bank conflicts, XCD-chunked L2-resident operands)
__device__ __forceinline__ void stage_one(const u16* g, int ld, u16* d, int tid) {
  int rw = tid >> 3;
  int gs = ((tid & 7) ^ (rw & 7)) << 3;
  int wb = (tid >> 6) << 9;
#pragma unroll
  for (int p = 0; p < 4; p++)
    GLOAD_LDS(g + (long)(p * 64 + rw) * ld + gs, d + p * 4096 + wb);
}

__device__ __forceinline__ void gemm256d(f32x4 (&acc)[8][4],
    const u16* Ag, int lda, const u16* Bg, int ldb, int nk,
    u16* As, u16* Bs, int tid) {
  const int lane = tid & 63, wid = tid >> 6;
  const int wr = (wid >> 2) << 7;
  const int wc = (wid & 3) << 6;
  const int rl = lane & 15, kg = lane >> 4;
  const int swz0 = (kg ^ (rl & 7)) << 3;
  const int rbA = (wr + rl) * 64, rbB = (wc + rl) * 64;

  stage_one(Ag, lda, As, tid);
  stage_one(Bg, ldb, Bs, tid);
  if (nk > 1) stage_one(Ag + 64, lda, As + 16384, tid);

  int ba = 0;
  for (int t = 0; t < nk; ++t) {
    if (t + 1 < nk) asm volatile("s_waitcnt vmcnt(4)" ::: "memory");
    else            asm volatile("s_waitcnt vmcnt(0)" ::: "memory");
    __builtin_amdgcn_s_barrier();
    if (t + 1 < nk)
      stage_one(Bg + (t + 1) * 64, ldb, Bs + ((t + 1) & 1) * 16384, tid);
    if (t + 2 < nk) {
      int nb = ba + 2; if (nb >= 3) nb -= 3;
      stage_one(Ag + (long)(t + 2) * 64, lda, As + nb * 16384, tid);
    }
    const u16* ab = As + ba * 16384 + rbA;
    const u16* bb = Bs + (t & 1) * 16384 + rbB;
#pragma unroll
    for (int kk = 0; kk < 2; kk++) {
      const int sw = swz0 ^ (kk << 5);
      bf16x8 a[8], b[4];
#pragma unroll
      for (int i = 0; i < 8; i++) a[i] = ds128(ab + i * 1024 + sw);
#pragma unroll
      for (int j = 0; j < 4; j++) b[j] = ds128(bb + j * 1024 + sw);
      asm volatile("s_waitcnt lgkmcnt(0)" ::: "memory");
      __builtin_amdgcn_sched_barrier(0);
      __builtin_amdgcn_s_setprio(1);
#pragma unroll
      for (int i = 0; i < 8; i++)
#pragma unroll
        for (int j = 0; j < 4; j++)
          acc[i][j] = __builtin_amdgcn_mfma_f32_16x16x32_bf16(a[i], b[j], acc[i][j], 0, 0, 0);
      __builtin_amdgcn_s_setprio(0);
      __builtin_amdgcn_sched_barrier(0);
    }
    ba = ba + 1; if (ba == 3) ba = 0;
  }
}

// ====== PV core: 256x128, BK=64, A in fp8 / B in bf16, 3-buffer never-drain ======
// LDS: As8[3][256 rows][64 B] = 48KB fp8, Bs[3][128 rows][128 B] = 48KB bf16.
// Swizzles (both staged-source and ds_read side, 16B granules):
//   A: granule g at g^(row&3) within 64B row; read ds_read_b64 at half (kg&1).
//   B: granule g at g^(row&7) within 128B row; read ds_read_b128.
// Schedule (r7-proven): stage(t+2) after barrier(t); steady wait vmcnt(4)
// (one 4-load stage in flight); drain only at the final tile.
__device__ __forceinline__ void stage_pv(const u8* gA, const u16* gB,
                                         u8* Ad, u8* Bd, int tid) {
  int w = tid >> 6;
#pragma unroll
  for (int pass = 0; pass < 2; pass++) {
    int gid = pass * 512 + tid;
    int ra = gid >> 2, ga = gid & 3;
    GLOAD_LDS(gA + (long)ra * 2048 + ((ga ^ (ra & 3)) << 4),
              Ad + pass * 8192 + w * 1024);
    int rb = gid >> 3, gb = gid & 7;
    GLOAD_LDS(gB + (long)rb * 2048 + ((gb ^ (rb & 7)) << 3),
              Bd + pass * 8192 + w * 1024);
  }
}

__device__ __forceinline__ void gemm_pv8(f32x4 (&acc)[4][4],
    const u8* Ag, const u16* Bg, u8* As, u8* Bs, int tid) {
  const int lane = tid & 63, wid = tid >> 6;
  const int mq = wid >> 1, nh = wid & 1;        // 4M x 2N waves, 64x64 each
  const int rl = lane & 15, kg = lane >> 4;
  const int nk = 32;

  stage_pv(Ag, Bg, As, Bs, tid);                          // t=0 -> buf0
  stage_pv(Ag + 64, Bg + 64, As + 16384, Bs + 16384, tid);// t=1 -> buf1
  int bsel = 0;
  for (int t = 0; t < nk; ++t) {
    if (t + 1 < nk) asm volatile("s_waitcnt vmcnt(4)" ::: "memory");
    else            asm volatile("s_waitcnt vmcnt(0)" ::: "memory");
    __builtin_amdgcn_s_barrier();
    if (t + 2 < nk) {
      int nb = bsel + 2; if (nb >= 3) nb -= 3;
      stage_pv(Ag + (long)(t + 2) * 64, Bg + (t + 2) * 64,
               As + nb * 16384, Bs + nb * 16384, tid);
    }
    const u8* ab = As + bsel * 16384 + (mq * 64 + rl) * 64 + ((kg & 1) << 3);
    const u8* bb = Bs + bsel * 16384 + (nh * 64 + rl) * 128;
#pragma unroll
    for (int kk = 0; kk < 2; kk++) {
      const int sa = (((kk << 1) + (kg >> 1)) ^ (rl & 3)) << 4;
      const int sb = (((kk << 2) + kg) ^ (rl & 7)) << 4;
      i32x2 ar[4]; bf16x8 bfr[4];
#pragma unroll
      for (int i = 0; i < 4; i++) ar[i] = ds64(ab + i * 1024 + sa);
#pragma unroll
      for (int j = 0; j < 4; j++) bfr[j] = ds128(bb + j * 2048 + sb);
      asm volatile("s_waitcnt lgkmcnt(0)" ::: "memory");
      __builtin_amdgcn_sched_barrier(0);
      bf16x8 a[4];
#pragma unroll
      for (int i = 0; i < 4; i++) a[i] = cvt8(ar[i]);
      __builtin_amdgcn_s_setprio(1);
#pragma unroll
      for (int i = 0; i < 4; i++)
#pragma unroll
        for (int j = 0; j < 4; j++)
          acc[i][j] = __builtin_amdgcn_mfma_f32_16x16x32_bf16(a[i], bfr[j], acc[i][j], 0, 0, 0);
      __builtin_amdgcn_s_setprio(0);
      __builtin_amdgcn_sched_barrier(0);
    }
    bsel = bsel + 1; if (bsel == 3) bsel = 0;
  }
}

// ---------------- conversion kernels ----------------
__global__ __launch_bounds__(256) void k_cvt2(const float* __restrict__ inX,
                                              const float* __restrict__ inY,
                                              u16* __restrict__ oX, u16* __restrict__ oY,
                                              int n8) {
  int i = blockIdx.x * 256 + threadIdx.x;
  const float* in = (i < n8) ? inX : inY;
  u16* out = (i < n8) ? oX : oY;
  int k = (i < n8) ? i : i - n8;
  const float4* pf = (const float4*)in + (long)k * 2;
  float4 a = pf[0], b = pf[1];
  u16x8 o;
  o[0] = f2bf(a.x); o[1] = f2bf(a.y); o[2] = f2bf(a.z); o[3] = f2bf(a.w);
  o[4] = f2bf(b.x); o[5] = f2bf(b.y); o[6] = f2bf(b.z); o[7] = f2bf(b.w);
  *((u16x8*)out + k) = o;
}

struct P6 { const float* p[6]; };
struct O6 { u16* p[6]; };

__global__ __launch_bounds__(256) void k_cvt_w(P6 w, u16* __restrict__ out) {
  int z = blockIdx.y;
  int i = blockIdx.x * 256 + threadIdx.x;
  const float4* pf = (const float4*)w.p[z] + (long)i * 2;
  float4 a = pf[0], b = pf[1];
  u16x8 o;
  o[0] = f2bf(a.x); o[1] = f2bf(a.y); o[2] = f2bf(a.z); o[3] = f2bf(a.w);
  o[4] = f2bf(b.x); o[5] = f2bf(b.y); o[6] = f2bf(b.z); o[7] = f2bf(b.w);
  *((u16x8*)(out + (long)z * 262144) + i) = o;
}

// ---------------- projections (old core, 1D bm-chunked grid) ----------------
__global__ __launch_bounds__(256) void k_proj(const u16* __restrict__ Xb, const u16* __restrict__ Yb,
                                              const u16* __restrict__ Wb, P6 bias, O6 dst) {
  __shared__ u16 As[12288], Bs[12288];
  int x = blockIdx.x;
  int swz = (x & 7) * 384 + (x >> 3);
  int bm = swz / 24;
  int r  = swz - bm * 24;
  int z = r >> 2, bn = r & 3;
  int tid = threadIdx.x, wave = tid >> 6, lane = tid & 63;
  const u16* Ag = (z < 3 ? Xb : Yb) + (long)bm * 128 * 512;
  const u16* Bg = Wb + (long)z * 262144 + (long)bn * 128 * 512;
  f32x4 acc[4][4] = {};
  gemm_seg(acc, Ag, Bg, 512, 512, 16, As, Bs, wave, lane);
  const float* bi = bias.p[z];
  u16* D = dst.p[z];
  int wr = (wave >> 1) << 6, wc = (wave & 1) << 6;
  int row0 = bm * 128 + wr + ((lane >> 4) << 2);
  int col0 = bn * 128 + wc + (lane & 15);
  float bj[4];
#pragma unroll
  for (int j = 0; j < 4; j++) bj[j] = bi[col0 + (j << 4)];
#pragma unroll
  for (int i = 0; i < 4; i++)
#pragma unroll
    for (int j = 0; j < 4; j++)
#pragma unroll
      for (int rr = 0; rr < 4; rr++)
        D[(long)(row0 + (i << 4) + rr) * 512 + col0 + (j << 4)] = f2bf(acc[i][j][rr] + bj[j]);
}

// ---------------- scores (gemm256d): XCD chunk = one batch b ----------------
__global__ __launch_bounds__(512) void k_s(const u16* __restrict__ Q, const u16* __restrict__ K,
                                           u16* __restrict__ S) {
  __shared__ u16 As[49152], Bs[32768];
  int x = blockIdx.x;
  int swz = (x & 7) * 64 + (x >> 3);         // 512 blocks, chunk=64 = one b
  int bn = swz & 7, bm = (swz >> 3) & 7, b = swz >> 6;
  int tid = threadIdx.x;
  const u16* Ag = Q + (long)b * 1048576 + (long)bm * 256 * 512;
  const u16* Bg = K + (long)b * 1048576 + (long)bn * 256 * 512;
  f32x4 acc[8][4] = {};
  gemm256d(acc, Ag, 512, Bg, 512, 8, As, Bs, tid);
  u16* D = S + (long)b * 4194304;
  const float scale = 0.04419417382415922f;  // 1/sqrt(512)
  int lane = tid & 63, wid = tid >> 6;
  int row0 = bm * 256 + ((wid >> 2) << 7) + ((lane >> 4) << 2);
  int col0 = bn * 256 + ((wid & 3) << 6) + (lane & 15);
#pragma unroll
  for (int i = 0; i < 8; i++)
#pragma unroll
    for (int j = 0; j < 4; j++)
#pragma unroll
      for (int rr = 0; rr < 4; rr++)
        D[(long)(row0 + (i << 4) + rr) * 2048 + col0 + (j << 4)] = f2bf(acc[i][j][rr] * scale);
}

// ---------------- softmax over batch axis -> fp8 e4m3 output ----------------
__global__ __launch_bounds__(256) void k_softmax8(const u16* __restrict__ S,
                                                  u8* __restrict__ A8) {
  int idx = blockIdx.x * 256 + threadIdx.x;   // 2048 blocks; 8 m-positions each
  u16x8 v[8];
#pragma unroll
  for (int b = 0; b < 8; b++) v[b] = *((const u16x8*)(S + (long)b * 4194304) + idx);
  unsigned w0[8], w1[8];
#pragma unroll
  for (int jp = 0; jp < 4; jp++) {
    float va[8], vb[8];
    {
      float e[8], m = -1e30f;
#pragma unroll
      for (int b = 0; b < 8; b++) { e[b] = bf2f(v[b][2 * jp]); m = fmaxf(m, e[b]); }
      float s = 0.f;
#pragma unroll
      for (int b = 0; b < 8; b++) { e[b] = __expf(e[b] - m); s += e[b]; }
      float inv = 1.0f / s;
#pragma unroll
      for (int b = 0; b < 8; b++) va[b] = e[b] * inv;
    }
    {
      float e[8], m = -1e30f;
#pragma unroll
      for (int b = 0; b < 8; b++) { e[b] = bf2f(v[b][2 * jp + 1]); m = fmaxf(m, e[b]); }
      float s = 0.f;
#pragma unroll
      for (int b = 0; b < 8; b++) { e[b] = __expf(e[b] - m); s += e[b]; }
      float inv = 1.0f / s;
#pragma unroll
      for (int b = 0; b < 8; b++) vb[b] = e[b] * inv;
    }
#pragma unroll
    for (int b = 0; b < 8; b++) {
      if (jp == 0)      w0[b] = __builtin_amdgcn_cvt_pk_fp8_f32(va[b], vb[b], 0,     false);
      else if (jp == 1) w0[b] = __builtin_amdgcn_cvt_pk_fp8_f32(va[b], vb[b], w0[b], true);
      else if (jp == 2) w1[b] = __builtin_amdgcn_cvt_pk_fp8_f32(va[b], vb[b], 0,     false);
      else              w1[b] = __builtin_amdgcn_cvt_pk_fp8_f32(va[b], vb[b], w1[b], true);
    }
  }
#pragma unroll
  for (int b = 0; b < 8; b++) {
    i32x2 w; w[0] = (int)w0[b]; w[1] = (int)w1[b];
    *(i32x2*)(A8 + (long)b * 4194304 + (long)idx * 8) = w;
  }
}

// ---------------- V transpose (bf16, unchanged) ----------------
__global__ __launch_bounds__(256) void k_tr(const u16* __restrict__ V1, const u16* __restrict__ V2,
                                            u16* __restrict__ T1, u16* __restrict__ T2) {
  __shared__ u16 tile[64][65];
  int z = blockIdx.z;
  const u16* src = (z < 8 ? V1 : V2) + (long)(z & 7) * 1048576;
  u16*       dst = (z < 8 ? T1 : T2) + (long)(z & 7) * 1048576;
  int n0 = blockIdx.x * 64, d0 = blockIdx.y * 64;
  int t = threadIdx.x;
  int r = t >> 2, cs = (t & 3) * 16;
  const u16x8* sp = (const u16x8*)(src + (long)(n0 + r) * 512 + d0 + cs);
  u16x8 a = sp[0], b = sp[1];
#pragma unroll
  for (int jj = 0; jj < 8; jj++) { tile[r][cs + jj] = a[jj]; tile[r][cs + 8 + jj] = b[jj]; }
  __syncthreads();
  u16x8 o0, o1;
#pragma unroll
  for (int jj = 0; jj < 8; jj++) { o0[jj] = tile[cs + jj][r]; o1[jj] = tile[cs + 8 + jj][r]; }
  u16x8* op = (u16x8*)(dst + (long)(d0 + r) * 2048 + n0 + cs);
  op[0] = o0; op[1] = o1;
}

// ---------------- PV (fp8-A core, full K): XCD chunk = one batch b ----------------
// mode 0: out = acc + X + Y ; mode 1: out += acc
__global__ __launch_bounds__(512) void k_pv8(const u8* __restrict__ A8, const u16* __restrict__ Vt,
                                             const float* __restrict__ X, const float* __restrict__ Y,
                                             float* __restrict__ out, int mode) {
  __shared__ u8 As[49152], Bs[49152];
  int x = blockIdx.x;
  int swz = (x & 7) * 32 + (x >> 3);         // 256 blocks, chunk=32 = one b
  int bn = swz & 3, bm = (swz >> 2) & 7, b = swz >> 5;
  int tid = threadIdx.x;
  const u8*  Ag = A8 + (long)b * 4194304 + (long)bm * 256 * 2048;
  const u16* Bg = Vt + (long)b * 1048576 + (long)bn * 128 * 2048;
  f32x4 acc[4][4] = {};
  gemm_pv8(acc, Ag, Bg, As, Bs, tid);
  int lane = tid & 63, wid = tid >> 6;
  int mq = wid >> 1, nh = wid & 1;
  int row0 = bm * 256 + mq * 64 + ((lane >> 4) << 2);
  int col0 = bn * 128 + nh * 64 + (lane & 15);
  long base = (long)b * 1048576;
#pragma unroll
  for (int i = 0; i < 4; i++)
#pragma unroll
    for (int j = 0; j < 4; j++)
#pragma unroll
      for (int rr = 0; rr < 4; rr++) {
        long idx = base + (long)(row0 + (i << 4) + rr) * 512 + col0 + (j << 4);
        float v = acc[i][j][rr];
        out[idx] = mode ? (out[idx] + v) : (v + X[idx] + Y[idx]);
      }
}

extern "C" void kernel_launch(void* const* d_in, const int* in_sizes, int n_in,
                              void* d_out, int out_size, void* d_ws, size_t ws_size,
                              hipStream_t stream) {
  const float* X = (const float*)d_in[0];
  const float* Y = (const float*)d_in[1];
  P6 wp, bp;
  for (int i = 0; i < 6; i++) { wp.p[i] = (const float*)d_in[2 + 2 * i]; bp.p[i] = (const float*)d_in[3 + 2 * i]; }

  const long NX = 8L * 2048 * 512;
  const long NS = 8L * 2048 * 2048;
  u16* p = (u16*)d_ws;
  u16* Xb = p;  p += NX;                  // bf16 X (reused as Vt1)
  u16* Yb = p;  p += NX;                  // bf16 Y (reused as Vt2)
  u16* Wb = p;  p += 6L * 512 * 512;
  u16* Q1 = p;  p += NX;                  // Q1+K2 adjacent -> A8_1 after S1
  u16* K2 = p;  p += NX;
  u16* Q2 = p;  p += NX;                  // Q2+K1 adjacent -> A8_2 after S2
  u16* K1 = p;  p += NX;
  u16* Sb = p;  p += NS;
  u16* V1 = Sb;
  u16* V2 = Sb + NX;
  u16* Vt1 = Xb;
  u16* Vt2 = Yb;
  u8* A8_2 = (u8*)Q2;                     // NS bytes = Q2+K1 region (33.5 MB)
  u8* A8_1 = (u8*)Q1;                     // NS bytes = Q1+K2 region (33.5 MB)
  (void)ws_size; (void)in_sizes; (void)n_in; (void)out_size;

  dim3 T(256);
  k_cvt2<<<dim3(8192), T, 0, stream>>>(X, Y, Xb, Yb, (int)(NX / 8));
  k_cvt_w<<<dim3(128, 6), T, 0, stream>>>(wp, Wb);
  O6 dst; dst.p[0] = Q1; dst.p[1] = K1; dst.p[2] = V1; dst.p[3] = Q2; dst.p[4] = K2; dst.p[5] = V2;
  k_proj<<<dim3(3072), T, 0, stream>>>(Xb, Yb, Wb, bp, dst);
  k_tr<<<dim3(32, 8, 16), T, 0, stream>>>(V1, V2, Vt1, Vt2);
  // attention 2 first: S2 = Q2.K1^T, softmax over b -> fp8 A8_2 (over dead Q2/K1),
  // out = A2.V1 + X + Y
  k_s<<<dim3(512), dim3(512), 0, stream>>>(Q2, K1, Sb);
  k_softmax8<<<dim3(2048), T, 0, stream>>>(Sb, A8_2);
  k_pv8<<<dim3(256), dim3(512), 0, stream>>>(A8_2, Vt1, X, Y, (float*)d_out, 0);
  // attention 1: S1 = Q1.K2^T, softmax -> fp8 A8_1 (over dead Q1/K2), out += A1.V2
  k_s<<<dim3(512), dim3(512), 0, stream>>>(Q1, K2, Sb);
  k_softmax8<<<dim3(2048), T, 0, stream>>>(Sb, A8_1);
  k_pv8<<<dim3(256), dim3(512), 0, stream>>>(A8_1, Vt2, X, Y, (float*)d_out, 1);
}